// Round 6
// baseline (291.191 us; speedup 1.0000x reference)
//
#include <hip/hip_runtime.h>

// MHA: B=4, S=1024, E=1024, H=16, D=64.
// fused_cast (bf16 casts + mask bias + d_out bias-init) ->
// fused QKV GEMM (32x32x16 MFMA, V stored in PV-fragment order, XCD bands) ->
// flash attention (S^T, no running max, register-prefetch pipelined K/V) ->
// output GEMM (32x32x16, split-K=2, fp32 atomic accumulate).

typedef unsigned short u16;
typedef __bf16 bf16x8 __attribute__((ext_vector_type(8)));
typedef __bf16 bf16x2 __attribute__((ext_vector_type(2)));
typedef short s16x4 __attribute__((ext_vector_type(4)));
typedef float f32x4 __attribute__((ext_vector_type(4)));
typedef float f32x16 __attribute__((ext_vector_type(16)));

struct alignas(8) us4_t { u16 x, y, z, w; };

__device__ __forceinline__ u16 f2bf(float x) {
  unsigned int u = __builtin_bit_cast(unsigned int, x);
  unsigned int r = u + 0x7fffu + ((u >> 16) & 1u);
  return (u16)(r >> 16);
}

__device__ __forceinline__ unsigned int pack2bf(float a, float b) {
#if __has_builtin(__builtin_amdgcn_cvt_pk_bf16_f32)
  bf16x2 r = __builtin_amdgcn_cvt_pk_bf16_f32(a, b);
  return __builtin_bit_cast(unsigned int, r);
#else
  return (unsigned int)f2bf(a) | ((unsigned int)f2bf(b) << 16);
#endif
}

__device__ __forceinline__ f32x4 zero4() {
  f32x4 z; z[0] = 0.f; z[1] = 0.f; z[2] = 0.f; z[3] = 0.f; return z;
}

__device__ __forceinline__ void async_copy16(const void* g, void* l) {
  __builtin_amdgcn_global_load_lds(
      (__attribute__((address_space(1))) void*)(uintptr_t)g,
      (__attribute__((address_space(3))) void*)l, 16, 0, 0);
}

// ---- fused cast: 7 bf16 casts + mask->log2-bias + d_out bias pre-init --------
__global__ void fused_cast(const float* __restrict__ q, const float* __restrict__ k,
                           const float* __restrict__ v, const float* __restrict__ wq,
                           const float* __restrict__ wk, const float* __restrict__ wv,
                           const float* __restrict__ wo, const int* __restrict__ mask,
                           const float* __restrict__ bo,
                           u16* __restrict__ qo, u16* __restrict__ ko, u16* __restrict__ vo,
                           u16* __restrict__ wqo, u16* __restrict__ wko, u16* __restrict__ wvo,
                           u16* __restrict__ woo, float* __restrict__ biasf,
                           float* __restrict__ dout) {
  const int blk = blockIdx.x;
  if (blk >= 16400) {
    // d_out bias pre-init: row r gets bo (out_gemm atomically accumulates on top)
    const int r = blk - 16400;  // 0..4095
    ((float4*)dout)[r * 256 + threadIdx.x] = ((const float4*)bo)[threadIdx.x];
    return;
  }
  if (blk >= 16384) {
    int i = (blk - 16384) * 256 + threadIdx.x;  // 0..4095
    biasf[i] = mask[i] ? 0.f : -1.4427e20f;
    return;
  }
  const float* src; u16* dst; int off;
  if (blk < 4096)       { src = q;  dst = qo;  off = blk; }
  else if (blk < 8192)  { src = k;  dst = ko;  off = blk - 4096; }
  else if (blk < 12288) { src = v;  dst = vo;  off = blk - 8192; }
  else if (blk < 13312) { src = wq; dst = wqo; off = blk - 12288; }
  else if (blk < 14336) { src = wk; dst = wko; off = blk - 13312; }
  else if (blk < 15360) { src = wv; dst = wvo; off = blk - 14336; }
  else                  { src = wo; dst = woo; off = blk - 15360; }
  const size_t i = (size_t)off * 256 + threadIdx.x;
  float4 f = ((const float4*)src)[i];
  unsigned int lo = pack2bf(f.x, f.y), hi = pack2bf(f.z, f.w);
  unsigned long long pk = (unsigned long long)lo | ((unsigned long long)hi << 32);
  ((unsigned long long*)dst)[i] = pk;
}

// ---------------- GEMM core, 32x32x16 MFMA ------------------------------------
// C[i,o] = sum_e A[i,e]*Bw[o,e] (+ bias).  M-tile 128, N-tile NT*64, BK=64.
// 4 waves (2x2); wave tile 64(m) x NT*32(n).
// A/B frag: m|n = lane&31, k = (lane>>5)*8 + j.
// C/D frag: col = lane&31, row = (reg&3) + 8*(reg>>2) + 4*(lane>>5).
template <bool OUT_BF16, int NT, bool ATOMIC>
__device__ __forceinline__ void gemm_core32(const u16* __restrict__ A,
                                            const u16* __restrict__ Bw,
                                            const float* __restrict__ bias,
                                            void* __restrict__ outp, bool trans,
                                            int m0, int n0, int it0, int itN) {
  __shared__ u16 lA[128 * 64];
  __shared__ u16 lB[NT * 64 * 64];
  const int tid = threadIdx.x;
  const int lane = tid & 63, w = tid >> 6;
  const int wm = w >> 1, wn = w & 1;
  const int l32 = lane & 31, hi = lane >> 5;
  const int rg = lane >> 3, cs = lane & 7;

  f32x16 acc[2][NT];
#pragma unroll
  for (int i = 0; i < 2; ++i)
#pragma unroll
    for (int j = 0; j < NT; ++j)
#pragma unroll
      for (int e = 0; e < 16; ++e) acc[i][j][e] = 0.f;

  for (int it = it0; it < itN; ++it) {
    const int k0 = it * 64;
#pragma unroll
    for (int t = 0; t < 4; ++t) {
      const int row = w * 32 + t * 8 + rg;
      const int c = cs ^ (row & 7);
      async_copy16(A + (size_t)(m0 + row) * 1024 + k0 + c * 8, &lA[(w * 32 + t * 8) * 64]);
    }
#pragma unroll
    for (int t = 0; t < NT * 2; ++t) {
      const int row = w * (NT * 16) + t * 8 + rg;
      const int c = cs ^ (row & 7);
      async_copy16(Bw + (size_t)(n0 + row) * 1024 + k0 + c * 8,
                   &lB[(w * (NT * 16) + t * 8) * 64]);
    }
    __syncthreads();
#pragma unroll
    for (int s = 0; s < 4; ++s) {
      bf16x8 af[2], bfr[NT];
#pragma unroll
      for (int i = 0; i < 2; ++i) {
        const int row = wm * 64 + i * 32 + l32;
        af[i] = *(const bf16x8*)&lA[row * 64 + (((s * 2 + hi) ^ (row & 7)) * 8)];
      }
#pragma unroll
      for (int j = 0; j < NT; ++j) {
        const int row = wn * (NT * 32) + j * 32 + l32;
        bfr[j] = *(const bf16x8*)&lB[row * 64 + (((s * 2 + hi) ^ (row & 7)) * 8)];
      }
#pragma unroll
      for (int i = 0; i < 2; ++i)
#pragma unroll
        for (int j = 0; j < NT; ++j)
          acc[i][j] = __builtin_amdgcn_mfma_f32_32x32x16_bf16(af[i], bfr[j], acc[i][j], 0, 0, 0);
    }
    __syncthreads();
  }

#pragma unroll
  for (int j = 0; j < NT; ++j) {
    const int cg = n0 + wn * (NT * 32) + j * 32 + l32;
    float bj = 0.f;
    if (!ATOMIC) bj = bias[cg];
#pragma unroll
    for (int i = 0; i < 2; ++i) {
      const int mbase = m0 + wm * 64 + i * 32 + 4 * hi;
#pragma unroll
      for (int g = 0; g < 4; ++g) {
        const int r0 = mbase + 8 * g;
        if (ATOMIC) {
          float* o = (float*)outp;
#pragma unroll
          for (int rr = 0; rr < 4; ++rr)
            unsafeAtomicAdd(&o[(size_t)(r0 + rr) * 1024 + cg], acc[i][j][g * 4 + rr]);
        } else if (!trans) {
          if (OUT_BF16) {
            u16* o = (u16*)outp;
#pragma unroll
            for (int rr = 0; rr < 4; ++rr)
              o[(size_t)(r0 + rr) * 1024 + cg] = f2bf(acc[i][j][g * 4 + rr] + bj);
          } else {
            float* o = (float*)outp;
#pragma unroll
            for (int rr = 0; rr < 4; ++rr)
              o[(size_t)(r0 + rr) * 1024 + cg] = acc[i][j][g * 4 + rr] + bj;
          }
        } else {
          // V store in PV-fragment order: Vt2[bh][s>>2][d][s&3]; r0 % 4 == 0.
          u16* o = (u16*)outp;
          const int bh = ((r0 >> 10) << 4) + (cg >> 6);
          const int g2 = (r0 & 1023) >> 2;
          const int d  = cg & 63;
          union { us4_t s; unsigned int u[2]; } pk;
          pk.u[0] = pack2bf(acc[i][j][g * 4 + 0] + bj, acc[i][j][g * 4 + 1] + bj);
          pk.u[1] = pack2bf(acc[i][j][g * 4 + 2] + bj, acc[i][j][g * 4 + 3] + bj);
          *(us4_t*)&o[(size_t)bh * 65536 + g2 * 256 + d * 4] = pk.s;
        }
      }
    }
  }
}

// qkv: grid 768 flat; each XCD owns 12 consecutive (m,z) bands of 8 n-blocks.
__global__ __launch_bounds__(256, 3) void qkv_gemm(
    const u16* __restrict__ Xq, const u16* __restrict__ Xk, const u16* __restrict__ Xv,
    const u16* __restrict__ Wq, const u16* __restrict__ Wk, const u16* __restrict__ Wv,
    const float* __restrict__ bq, const float* __restrict__ bk, const float* __restrict__ bv,
    u16* __restrict__ Qo, u16* __restrict__ Ko, u16* __restrict__ Vto) {
  const int flat = blockIdx.x;
  const int xcd = flat & 7, t = flat >> 3;
  const int n = t & 7, bandl = t >> 3;        // bandl 0..11
  const int band = xcd * 12 + bandl;          // 0..95
  const int z = band >> 5, m = band & 31;
  const u16* A = (z == 0) ? Xq : (z == 1) ? Xk : Xv;
  const u16* W = (z == 0) ? Wq : (z == 1) ? Wk : Wv;
  const float* bias = (z == 0) ? bq : (z == 1) ? bk : bv;
  u16* out = (z == 0) ? Qo : (z == 1) ? Ko : Vto;
  gemm_core32<true, 2, false>(A, W, bias, out, z == 2, m * 128, n * 128, 0, 16);
}

// out: grid 1024 flat; split-K=2; xcd owns 4 m-bands x 16 n x 2 k-halves.
__global__ __launch_bounds__(256, 4) void out_gemm(
    const u16* __restrict__ A, const u16* __restrict__ W,
    float* __restrict__ out) {
  const int flat = blockIdx.x;
  const int xcd = flat & 7, t = flat >> 3;    // t 0..127
  const int kh = t & 1, s = t >> 1;           // s 0..63
  const int n = s & 15, m = xcd * 4 + (s >> 4);
  gemm_core32<false, 1, true>(A, W, nullptr, out, false, m * 128, n * 64,
                              kh * 8, kh * 8 + 8);
}

// ---------------- flash attention, S^T, no max, reg-prefetch pipeline ---------
// Grid 1024 (XCD-swizzled). Block 256 = 4 waves x 16 q rows; 128 keys/iter x 8.
// Per iter: barrier -> ds_write K/V tile from regs -> issue global loads for
// iter+1 -> barrier -> compute. Global latency hidden behind compute phase.
__global__ __launch_bounds__(256, 4) void attn_kernel(
    const u16* __restrict__ Qb, const u16* __restrict__ Kb, const u16* __restrict__ Vtb,
    const float* __restrict__ biasf, u16* __restrict__ Ob) {
  __shared__ u16 lK[128 * 64];
  __shared__ u16 lV[64 * 128];  // Vt2 slab, identity layout
  u16* lQ = lV;                 // prologue-only alias

  const int tid = threadIdx.x;
  const int lane = tid & 63, w = tid >> 6;
  const int quad = lane >> 4, l16 = lane & 15;
  const int rg = lane >> 3, cs = lane & 7;
  const int c = cs ^ (rg & 7);  // staging chunk swizzle (t/it-invariant)

  const int flat = blockIdx.x;
  const int xcd = flat & 7, r = flat >> 3;
  const int bh = xcd * 8 + (r & 7), qt = r >> 3;
  const int b = bh >> 4;
  const size_t qkBase = (size_t)b * 1048576 + (size_t)(bh & 15) * 64;
  const size_t vBase = (size_t)bh * 65536;
  const float C = 0.0450842200277982f;  // (1/sqrt(E)) * log2(e)
  const float* bp = biasf + b * 1024 + quad * 4;

  // stage Q (64 q rows x 64 d) into the lV-aliased region
#pragma unroll
  for (int t = 0; t < 2; ++t) {
    async_copy16(Qb + qkBase + (size_t)(qt * 64 + w * 16 + t * 8 + rg) * 1024 + c * 8,
                 &lQ[(w * 16 + t * 8) * 64]);
  }
  __syncthreads();

  bf16x8 qf[2];
#pragma unroll
  for (int kk = 0; kk < 2; ++kk) {
    const int row = w * 16 + l16;
    qf[kk] = *(const bf16x8*)&lQ[row * 64 + (((kk * 4 + quad) ^ (row & 7)) * 8)];
  }
  // loop-top barrier protects lQ before lV writes

  // per-thread staging sources
  const u16* kSrc = Kb + qkBase + (size_t)(w * 32 + rg) * 1024 + c * 8;
  const u16* vSrc = Vtb + vBase + (w * 4) * 512 + lane * 8;

  uint4 kpre[4], vpre[4];
#pragma unroll
  for (int t = 0; t < 4; ++t) kpre[t] = *(const uint4*)(kSrc + (size_t)(t * 8) * 1024);
#pragma unroll
  for (int t = 0; t < 4; ++t) vpre[t] = *(const uint4*)(vSrc + t * 512);

  float lsum = 0.f;
  f32x4 oacc[4];
#pragma unroll
  for (int dt = 0; dt < 4; ++dt) oacc[dt] = zero4();

  for (int it = 0; it < 8; ++it) {
    const int k0 = it * 128;
    __syncthreads();  // all waves done reading lK/lV (and lQ on iter 0)
#pragma unroll
    for (int t = 0; t < 4; ++t)
      *(uint4*)&lK[(w * 32 + t * 8 + rg) * 64 + cs * 8] = kpre[t];
#pragma unroll
    for (int t = 0; t < 4; ++t)
      *(uint4*)&lV[(w * 4 + t) * 512 + lane * 8] = vpre[t];
    // prefetch next tile (lands during compute phase)
    const int nit = (it < 7) ? it + 1 : 7;
#pragma unroll
    for (int t = 0; t < 4; ++t)
      kpre[t] = *(const uint4*)(kSrc + (size_t)(nit * 128 + t * 8) * 1024);
#pragma unroll
    for (int t = 0; t < 4; ++t)
      vpre[t] = *(const uint4*)(vSrc + (size_t)nit * 8192 + t * 512);
    __syncthreads();

    // S^T: sacc[n] = keys n*16.. ; lane: q=l16, key=n*16+quad*4+r
    f32x4 sacc[8];
#pragma unroll
    for (int n = 0; n < 8; ++n) sacc[n] = zero4();
#pragma unroll
    for (int kk = 0; kk < 2; ++kk) {
#pragma unroll
      for (int n = 0; n < 8; ++n) {
        const int row = n * 16 + l16;
        bf16x8 kf = *(const bf16x8*)&lK[row * 64 + (((kk * 4 + quad) ^ (row & 7)) * 8)];
        sacc[n] = __builtin_amdgcn_mfma_f32_16x16x32_bf16(kf, qf[kk], sacc[n], 0, 0, 0);
      }
    }

    // p = exp2(C*s + bias); row sums
    f32x4 sum4 = zero4();
#pragma unroll
    for (int n = 0; n < 8; ++n) {
      const float4 vb = *(const float4*)&bp[k0 + n * 16];
      sacc[n][0] = __builtin_amdgcn_exp2f(fmaf(sacc[n][0], C, vb.x));
      sacc[n][1] = __builtin_amdgcn_exp2f(fmaf(sacc[n][1], C, vb.y));
      sacc[n][2] = __builtin_amdgcn_exp2f(fmaf(sacc[n][2], C, vb.z));
      sacc[n][3] = __builtin_amdgcn_exp2f(fmaf(sacc[n][3], C, vb.w));
      sum4[0] += sacc[n][0]; sum4[1] += sacc[n][1];
      sum4[2] += sacc[n][2]; sum4[3] += sacc[n][3];
    }

    // pack P (B operand of 16x16x16: n=q=l16, k=quad*4+j)
    s16x4 pf[8];
#pragma unroll
    for (int n = 0; n < 8; ++n) {
      union { s16x4 v; unsigned int u[2]; } pu;
      pu.u[0] = pack2bf(sacc[n][0], sacc[n][1]);
      pu.u[1] = pack2bf(sacc[n][2], sacc[n][3]);
      pf[n] = pu.v;
    }

    // O^T += V^T P^T
#pragma unroll
    for (int dt = 0; dt < 4; ++dt) {
      const int dbase = (dt * 16 + l16) * 4;
#pragma unroll
      for (int ks = 0; ks < 8; ++ks) {
        s16x4 vf = *(const s16x4*)&lV[(ks * 4 + quad) * 256 + dbase];
        oacc[dt] = __builtin_amdgcn_mfma_f32_16x16x16bf16_1k(vf, pf[ks], oacc[dt], 0, 0, 0);
      }
    }

    // lsum reduction (off the PV critical path)
    float rs = (sum4[0] + sum4[1]) + (sum4[2] + sum4[3]);
    rs += __shfl_xor(rs, 16);
    rs += __shfl_xor(rs, 32);
    lsum += rs;
  }

  const float inv = 1.f / lsum;
  const int qg = qt * 64 + w * 16 + l16;
#pragma unroll
  for (int dt = 0; dt < 4; ++dt) {
    union { us4_t s; unsigned int u[2]; } pk;
    pk.u[0] = pack2bf(oacc[dt][0] * inv, oacc[dt][1] * inv);
    pk.u[1] = pack2bf(oacc[dt][2] * inv, oacc[dt][3] * inv);
    *(us4_t*)&Ob[qkBase + (size_t)qg * 1024 + dt * 16 + quad * 4] = pk.s;
  }
}

extern "C" void kernel_launch(void* const* d_in, const int* in_sizes, int n_in,
                              void* d_out, int out_size, void* d_ws, size_t ws_size,
                              hipStream_t stream) {
  const float* value  = (const float*)d_in[0];
  const float* key_in = (const float*)d_in[1];
  const float* query  = (const float*)d_in[2];
  const int*   mask   = (const int*)d_in[3];
  const float* Wq = (const float*)d_in[4];
  const float* bq = (const float*)d_in[5];
  const float* Wk = (const float*)d_in[6];
  const float* bk = (const float*)d_in[7];
  const float* Wv = (const float*)d_in[8];
  const float* bv = (const float*)d_in[9];
  const float* Wo = (const float*)d_in[10];
  const float* bo = (const float*)d_in[11];

  u16* ws = (u16*)d_ws;
  u16* q_bf  = ws;              // 4096x1024 (consumed by qkv; reused as attnb)
  u16* k_bf  = ws + 4194304;
  u16* v_bf  = ws + 8388608;
  u16* wq_bf = ws + 12582912;   // 1024x1024 each
  u16* wk_bf = ws + 13631488;
  u16* wv_bf = ws + 14680064;
  u16* wo_bf = ws + 15728640;
  u16* Qbuf  = ws + 16777216;   // (b,s,h*64+d)
  u16* Kbuf  = ws + 20971520;
  u16* Vtbuf = ws + 25165824;   // Vt2[bh][s>>2][d][s&3]
  u16* attnb = q_bf;            // alias: q_bf is dead after qkv_gemm
  float* biasf = (float*)(ws + 29360128);  // 4096 floats

  fused_cast<<<20496, 256, 0, stream>>>(query, key_in, value, Wq, Wk, Wv, Wo, mask,
                                        bo, q_bf, k_bf, v_bf, wq_bf, wk_bf, wv_bf,
                                        wo_bf, biasf, (float*)d_out);
  qkv_gemm<<<dim3(768), 256, 0, stream>>>(q_bf, k_bf, v_bf, wq_bf, wk_bf, wv_bf,
                                          bq, bk, bv, Qbuf, Kbuf, Vtbuf);
  attn_kernel<<<dim3(1024), 256, 0, stream>>>(Qbuf, Kbuf, Vtbuf, biasf, attnb);
  out_gemm<<<dim3(1024), 256, 0, stream>>>(attnb, wo_bf, (float*)d_out);
}

// Round 7
// 223.136 us; speedup vs baseline: 1.3050x; 1.3050x over previous
//
#include <hip/hip_runtime.h>

// MHA: B=4, S=1024, E=1024, H=16, D=64.
// fused_cast (weights->bf16 + mask bias) -> fused QKV GEMM (fp32 X staged with
// inline cast, 32x32x16 MFMA, V stored in PV-fragment order, XCD bands) ->
// flash attention (S^T, no running max) -> output GEMM (32x32x16).

typedef unsigned short u16;
typedef __bf16 bf16x8 __attribute__((ext_vector_type(8)));
typedef __bf16 bf16x2 __attribute__((ext_vector_type(2)));
typedef short s16x4 __attribute__((ext_vector_type(4)));
typedef float f32x4 __attribute__((ext_vector_type(4)));
typedef float f32x16 __attribute__((ext_vector_type(16)));

struct alignas(8) us4_t { u16 x, y, z, w; };

__device__ __forceinline__ u16 f2bf(float x) {
  unsigned int u = __builtin_bit_cast(unsigned int, x);
  unsigned int r = u + 0x7fffu + ((u >> 16) & 1u);
  return (u16)(r >> 16);
}

__device__ __forceinline__ unsigned int pack2bf(float a, float b) {
#if __has_builtin(__builtin_amdgcn_cvt_pk_bf16_f32)
  bf16x2 r = __builtin_amdgcn_cvt_pk_bf16_f32(a, b);
  return __builtin_bit_cast(unsigned int, r);
#else
  return (unsigned int)f2bf(a) | ((unsigned int)f2bf(b) << 16);
#endif
}

__device__ __forceinline__ f32x4 zero4() {
  f32x4 z; z[0] = 0.f; z[1] = 0.f; z[2] = 0.f; z[3] = 0.f; return z;
}

__device__ __forceinline__ void async_copy16(const void* g, void* l) {
  __builtin_amdgcn_global_load_lds(
      (__attribute__((address_space(1))) void*)(uintptr_t)g,
      (__attribute__((address_space(3))) void*)l, 16, 0, 0);
}

// ---- fused cast: 4 weight tensors -> bf16, mask -> log2-domain bias ----------
__global__ void fused_cast(const float* __restrict__ wq, const float* __restrict__ wk,
                           const float* __restrict__ wv, const float* __restrict__ wo,
                           const int* __restrict__ mask,
                           u16* __restrict__ wqo, u16* __restrict__ wko,
                           u16* __restrict__ wvo, u16* __restrict__ woo,
                           float* __restrict__ biasf) {
  const int blk = blockIdx.x;
  if (blk >= 4096) {
    int i = (blk - 4096) * 256 + threadIdx.x;  // 0..4095
    biasf[i] = mask[i] ? 0.f : -1.4427e20f;
    return;
  }
  const float* src; u16* dst; int off;
  if (blk < 1024)       { src = wq; dst = wqo; off = blk; }
  else if (blk < 2048)  { src = wk; dst = wko; off = blk - 1024; }
  else if (blk < 3072)  { src = wv; dst = wvo; off = blk - 2048; }
  else                  { src = wo; dst = woo; off = blk - 3072; }
  const size_t i = (size_t)off * 256 + threadIdx.x;
  float4 f = ((const float4*)src)[i];
  unsigned int lo = pack2bf(f.x, f.y), hi = pack2bf(f.z, f.w);
  unsigned long long pk = (unsigned long long)lo | ((unsigned long long)hi << 32);
  ((unsigned long long*)dst)[i] = pk;
}

// ---------------- GEMM core, 32x32x16 MFMA ------------------------------------
// C[i,o] = sum_e A[i,e]*Bw[o,e] + bias[o].  M-tile 128, N-tile NT*64, BK=64.
// 4 waves (2x2); wave tile 64(m) x NT*32(n).
// A/B frag: m|n = lane&31, k = (lane>>5)*8 + j.
// C/D frag: col = lane&31, row = (reg&3) + 8*(reg>>2) + 4*(lane>>5).
// AFP32: A is fp32 in global; staged via vector load + cvt_pk + ds_write_b128
// into the SAME LDS layout the async path produces.
template <bool OUT_BF16, int NT, bool AFP32>
__device__ __forceinline__ void gemm_core32(const void* __restrict__ Ap,
                                            const u16* __restrict__ Bw,
                                            const float* __restrict__ bias,
                                            void* __restrict__ outp, bool trans,
                                            int m0, int n0) {
  __shared__ u16 lA[128 * 64];
  __shared__ u16 lB[NT * 64 * 64];
  const int tid = threadIdx.x;
  const int lane = tid & 63, w = tid >> 6;
  const int wm = w >> 1, wn = w & 1;
  const int l32 = lane & 31, hi = lane >> 5;
  const int rg = lane >> 3, cs = lane & 7;

  f32x16 acc[2][NT];
#pragma unroll
  for (int i = 0; i < 2; ++i)
#pragma unroll
    for (int j = 0; j < NT; ++j)
#pragma unroll
      for (int e = 0; e < 16; ++e) acc[i][j][e] = 0.f;

  for (int it = 0; it < 16; ++it) {
    const int k0 = it * 64;
    if (AFP32) {
      const float* Af = (const float*)Ap;
#pragma unroll
      for (int t = 0; t < 4; ++t) {
        const int row = w * 32 + t * 8 + rg;
        const int c = cs ^ (row & 7);
        const float* p = Af + (size_t)(m0 + row) * 1024 + k0 + c * 8;
        float4 f0 = *(const float4*)p;
        float4 f1 = *(const float4*)(p + 4);
        uint4 pk;
        pk.x = pack2bf(f0.x, f0.y); pk.y = pack2bf(f0.z, f0.w);
        pk.z = pack2bf(f1.x, f1.y); pk.w = pack2bf(f1.z, f1.w);
        *(uint4*)&lA[row * 64 + cs * 8] = pk;
      }
    } else {
      const u16* Au = (const u16*)Ap;
#pragma unroll
      for (int t = 0; t < 4; ++t) {
        const int row = w * 32 + t * 8 + rg;
        const int c = cs ^ (row & 7);
        async_copy16(Au + (size_t)(m0 + row) * 1024 + k0 + c * 8,
                     &lA[(w * 32 + t * 8) * 64]);
      }
    }
#pragma unroll
    for (int t = 0; t < NT * 2; ++t) {
      const int row = w * (NT * 16) + t * 8 + rg;
      const int c = cs ^ (row & 7);
      async_copy16(Bw + (size_t)(n0 + row) * 1024 + k0 + c * 8,
                   &lB[(w * (NT * 16) + t * 8) * 64]);
    }
    __syncthreads();
#pragma unroll
    for (int s = 0; s < 4; ++s) {
      bf16x8 af[2], bfr[NT];
#pragma unroll
      for (int i = 0; i < 2; ++i) {
        const int row = wm * 64 + i * 32 + l32;
        af[i] = *(const bf16x8*)&lA[row * 64 + (((s * 2 + hi) ^ (row & 7)) * 8)];
      }
#pragma unroll
      for (int j = 0; j < NT; ++j) {
        const int row = wn * (NT * 32) + j * 32 + l32;
        bfr[j] = *(const bf16x8*)&lB[row * 64 + (((s * 2 + hi) ^ (row & 7)) * 8)];
      }
#pragma unroll
      for (int i = 0; i < 2; ++i)
#pragma unroll
        for (int j = 0; j < NT; ++j)
          acc[i][j] = __builtin_amdgcn_mfma_f32_32x32x16_bf16(af[i], bfr[j], acc[i][j], 0, 0, 0);
    }
    __syncthreads();
  }

#pragma unroll
  for (int j = 0; j < NT; ++j) {
    const int cg = n0 + wn * (NT * 32) + j * 32 + l32;
    const float bj = bias[cg];
#pragma unroll
    for (int i = 0; i < 2; ++i) {
      const int mbase = m0 + wm * 64 + i * 32 + 4 * hi;
#pragma unroll
      for (int g = 0; g < 4; ++g) {
        const int r0 = mbase + 8 * g;
        if (!trans) {
          if (OUT_BF16) {
            u16* o = (u16*)outp;
#pragma unroll
            for (int rr = 0; rr < 4; ++rr)
              o[(size_t)(r0 + rr) * 1024 + cg] = f2bf(acc[i][j][g * 4 + rr] + bj);
          } else {
            float* o = (float*)outp;
#pragma unroll
            for (int rr = 0; rr < 4; ++rr)
              o[(size_t)(r0 + rr) * 1024 + cg] = acc[i][j][g * 4 + rr] + bj;
          }
        } else {
          // V store in PV-fragment order: Vt2[bh][s>>2][d][s&3]; r0 % 4 == 0.
          u16* o = (u16*)outp;
          const int bh = ((r0 >> 10) << 4) + (cg >> 6);
          const int g2 = (r0 & 1023) >> 2;
          const int d  = cg & 63;
          union { us4_t s; unsigned int u[2]; } pk;
          pk.u[0] = pack2bf(acc[i][j][g * 4 + 0] + bj, acc[i][j][g * 4 + 1] + bj);
          pk.u[1] = pack2bf(acc[i][j][g * 4 + 2] + bj, acc[i][j][g * 4 + 3] + bj);
          *(us4_t*)&o[(size_t)bh * 65536 + g2 * 256 + d * 4] = pk.s;
        }
      }
    }
  }
}

// qkv: grid 768 flat; each XCD owns 12 consecutive (m,z) bands of 8 n-blocks.
// A operands are the raw fp32 activations (cast fused into staging).
__global__ __launch_bounds__(256, 3) void qkv_gemm(
    const float* __restrict__ Xq, const float* __restrict__ Xk, const float* __restrict__ Xv,
    const u16* __restrict__ Wq, const u16* __restrict__ Wk, const u16* __restrict__ Wv,
    const float* __restrict__ bq, const float* __restrict__ bk, const float* __restrict__ bv,
    u16* __restrict__ Qo, u16* __restrict__ Ko, u16* __restrict__ Vto) {
  const int flat = blockIdx.x;
  const int xcd = flat & 7, t = flat >> 3;
  const int n = t & 7, bandl = t >> 3;        // bandl 0..11
  const int band = xcd * 12 + bandl;          // 0..95
  const int z = band >> 5, m = band & 31;
  const float* A = (z == 0) ? Xq : (z == 1) ? Xk : Xv;
  const u16* W = (z == 0) ? Wq : (z == 1) ? Wk : Wv;
  const float* bias = (z == 0) ? bq : (z == 1) ? bk : bv;
  u16* out = (z == 0) ? Qo : (z == 1) ? Ko : Vto;
  gemm_core32<true, 2, true>(A, W, bias, out, z == 2, m * 128, n * 128);
}

// out: grid 512 flat; xcd owns 4 m-bands of 16 n-blocks each.
__global__ __launch_bounds__(256, 2) void out_gemm(
    const u16* __restrict__ A, const u16* __restrict__ W,
    const float* __restrict__ bias, float* __restrict__ out) {
  const int flat = blockIdx.x;
  const int xcd = flat & 7, t = flat >> 3;
  const int n = t & 15, m = xcd * 4 + (t >> 4);
  gemm_core32<false, 1, false>(A, W, bias, out, false, m * 128, n * 64);
}

// ---------------- flash attention, S^T orientation, no running max ------------
// Grid 1024 (XCD-swizzled). Block 256 = 4 waves x 16 q rows; 128 keys/iter x 8.
__global__ __launch_bounds__(256, 4) void attn_kernel(
    const u16* __restrict__ Qb, const u16* __restrict__ Kb, const u16* __restrict__ Vtb,
    const float* __restrict__ biasf, u16* __restrict__ Ob) {
  __shared__ u16 lK[128 * 64];
  __shared__ u16 lV[64 * 128];  // Vt2 slab, identity layout
  u16* lQ = lV;                 // prologue-only alias

  const int tid = threadIdx.x;
  const int lane = tid & 63, w = tid >> 6;
  const int quad = lane >> 4, l16 = lane & 15;
  const int rg = lane >> 3, cs = lane & 7;

  const int flat = blockIdx.x;
  const int xcd = flat & 7, r = flat >> 3;
  const int bh = xcd * 8 + (r & 7), qt = r >> 3;
  const int b = bh >> 4;
  const size_t qkBase = (size_t)b * 1048576 + (size_t)(bh & 15) * 64;
  const size_t vBase = (size_t)bh * 65536;
  const float C = 0.0450842200277982f;  // (1/sqrt(E)) * log2(e)
  const float* bp = biasf + b * 1024 + quad * 4;

#pragma unroll
  for (int t = 0; t < 2; ++t) {
    const int row = w * 16 + t * 8 + rg;
    const int c = cs ^ (row & 7);
    async_copy16(Qb + qkBase + (size_t)(qt * 64 + row) * 1024 + c * 8,
                 &lQ[(w * 16 + t * 8) * 64]);
  }
  __syncthreads();

  bf16x8 qf[2];
#pragma unroll
  for (int kk = 0; kk < 2; ++kk) {
    const int row = w * 16 + l16;
    qf[kk] = *(const bf16x8*)&lQ[row * 64 + (((kk * 4 + quad) ^ (row & 7)) * 8)];
  }
  __syncthreads();  // protect lQ before lV staging overwrites it

  float lsum = 0.f;
  f32x4 oacc[4];
#pragma unroll
  for (int dt = 0; dt < 4; ++dt) oacc[dt] = zero4();

  for (int it = 0; it < 8; ++it) {
    const int k0 = it * 128;
#pragma unroll
    for (int t = 0; t < 4; ++t) {
      const int row = w * 32 + t * 8 + rg;
      const int c = cs ^ (row & 7);
      async_copy16(Kb + qkBase + (size_t)(k0 + row) * 1024 + c * 8,
                   &lK[(w * 32 + t * 8) * 64]);
    }
#pragma unroll
    for (int t = 0; t < 4; ++t) {
      const int o16 = (w * 4 + t) * 512 + lane * 8;
      async_copy16(Vtb + vBase + (size_t)it * 8192 + o16, &lV[(w * 4 + t) * 512]);
    }
    __syncthreads();

    f32x4 sacc[8];
#pragma unroll
    for (int n = 0; n < 8; ++n) sacc[n] = zero4();
#pragma unroll
    for (int kk = 0; kk < 2; ++kk) {
#pragma unroll
      for (int n = 0; n < 8; ++n) {
        const int row = n * 16 + l16;
        bf16x8 kf = *(const bf16x8*)&lK[row * 64 + (((kk * 4 + quad) ^ (row & 7)) * 8)];
        sacc[n] = __builtin_amdgcn_mfma_f32_16x16x32_bf16(kf, qf[kk], sacc[n], 0, 0, 0);
      }
    }

    f32x4 sum4 = zero4();
#pragma unroll
    for (int n = 0; n < 8; ++n) {
      const float4 vb = *(const float4*)&bp[k0 + n * 16];
      sacc[n][0] = __builtin_amdgcn_exp2f(fmaf(sacc[n][0], C, vb.x));
      sacc[n][1] = __builtin_amdgcn_exp2f(fmaf(sacc[n][1], C, vb.y));
      sacc[n][2] = __builtin_amdgcn_exp2f(fmaf(sacc[n][2], C, vb.z));
      sacc[n][3] = __builtin_amdgcn_exp2f(fmaf(sacc[n][3], C, vb.w));
      sum4[0] += sacc[n][0]; sum4[1] += sacc[n][1];
      sum4[2] += sacc[n][2]; sum4[3] += sacc[n][3];
    }

    s16x4 pf[8];
#pragma unroll
    for (int n = 0; n < 8; ++n) {
      union { s16x4 v; unsigned int u[2]; } pu;
      pu.u[0] = pack2bf(sacc[n][0], sacc[n][1]);
      pu.u[1] = pack2bf(sacc[n][2], sacc[n][3]);
      pf[n] = pu.v;
    }

#pragma unroll
    for (int dt = 0; dt < 4; ++dt) {
      const int dbase = (dt * 16 + l16) * 4;
#pragma unroll
      for (int ks = 0; ks < 8; ++ks) {
        s16x4 vf = *(const s16x4*)&lV[(ks * 4 + quad) * 256 + dbase];
        oacc[dt] = __builtin_amdgcn_mfma_f32_16x16x16bf16_1k(vf, pf[ks], oacc[dt], 0, 0, 0);
      }
    }

    // lsum reduction off the PV critical path
    float rs = (sum4[0] + sum4[1]) + (sum4[2] + sum4[3]);
    rs += __shfl_xor(rs, 16);
    rs += __shfl_xor(rs, 32);
    lsum += rs;
    __syncthreads();
  }

  const float inv = 1.f / lsum;
  const int qg = qt * 64 + w * 16 + l16;
#pragma unroll
  for (int dt = 0; dt < 4; ++dt) {
    union { us4_t s; unsigned int u[2]; } pk;
    pk.u[0] = pack2bf(oacc[dt][0] * inv, oacc[dt][1] * inv);
    pk.u[1] = pack2bf(oacc[dt][2] * inv, oacc[dt][3] * inv);
    *(us4_t*)&Ob[qkBase + (size_t)qg * 1024 + dt * 16 + quad * 4] = pk.s;
  }
}

extern "C" void kernel_launch(void* const* d_in, const int* in_sizes, int n_in,
                              void* d_out, int out_size, void* d_ws, size_t ws_size,
                              hipStream_t stream) {
  const float* value  = (const float*)d_in[0];
  const float* key_in = (const float*)d_in[1];
  const float* query  = (const float*)d_in[2];
  const int*   mask   = (const int*)d_in[3];
  const float* Wq = (const float*)d_in[4];
  const float* bq = (const float*)d_in[5];
  const float* Wk = (const float*)d_in[6];
  const float* bk = (const float*)d_in[7];
  const float* Wv = (const float*)d_in[8];
  const float* bv = (const float*)d_in[9];
  const float* Wo = (const float*)d_in[10];
  const float* bo = (const float*)d_in[11];

  u16* ws = (u16*)d_ws;
  u16* wq_bf = ws + 12582912;   // 1024x1024 each
  u16* wk_bf = ws + 13631488;
  u16* wv_bf = ws + 14680064;
  u16* wo_bf = ws + 15728640;
  u16* Qbuf  = ws + 16777216;   // (b,s,h*64+d)
  u16* Kbuf  = ws + 20971520;
  u16* Vtbuf = ws + 25165824;   // Vt2[bh][s>>2][d][s&3]
  u16* attnb = ws;              // (b,s,h*64+d)
  float* biasf = (float*)d_out; // consumed by attn, then overwritten by out_gemm

  fused_cast<<<4112, 256, 0, stream>>>(Wq, Wk, Wv, Wo, mask,
                                       wq_bf, wk_bf, wv_bf, wo_bf, biasf);
  qkv_gemm<<<dim3(768), 256, 0, stream>>>(query, key_in, value, wq_bf, wk_bf, wv_bf,
                                          bq, bk, bv, Qbuf, Kbuf, Vtbuf);
  attn_kernel<<<dim3(1024), 256, 0, stream>>>(Qbuf, Kbuf, Vtbuf, biasf, attnb);
  out_gemm<<<dim3(512), 256, 0, stream>>>(attnb, wo_bf, bo, (float*)d_out);
}

// Round 10
// 222.902 us; speedup vs baseline: 1.3064x; 1.0010x over previous
//
#include <hip/hip_runtime.h>

// MHA: B=4, S=1024, E=1024, H=16, D=64.
// fused_cast (X,W->bf16 + mask bias + d_out bias-init) ->
// fused QKV GEMM (32x32x16 MFMA, V in PV-fragment order, XCD bands) ->
// flash attention (S^T, no running max) ->
// output GEMM (32x32x16, split-K=2, fp32 atomic accumulate).
// All pieces individually correctness-validated in earlier rounds.

typedef unsigned short u16;
typedef __bf16 bf16x8 __attribute__((ext_vector_type(8)));
typedef __bf16 bf16x2 __attribute__((ext_vector_type(2)));
typedef short s16x4 __attribute__((ext_vector_type(4)));
typedef float f32x4 __attribute__((ext_vector_type(4)));
typedef float f32x16 __attribute__((ext_vector_type(16)));

struct alignas(8) us4_t { u16 x, y, z, w; };

__device__ __forceinline__ u16 f2bf(float x) {
  unsigned int u = __builtin_bit_cast(unsigned int, x);
  unsigned int r = u + 0x7fffu + ((u >> 16) & 1u);
  return (u16)(r >> 16);
}

__device__ __forceinline__ unsigned int pack2bf(float a, float b) {
#if __has_builtin(__builtin_amdgcn_cvt_pk_bf16_f32)
  bf16x2 r = __builtin_amdgcn_cvt_pk_bf16_f32(a, b);
  return __builtin_bit_cast(unsigned int, r);
#else
  return (unsigned int)f2bf(a) | ((unsigned int)f2bf(b) << 16);
#endif
}

__device__ __forceinline__ unsigned long long pack4bf(float4 f) {
  unsigned int lo = pack2bf(f.x, f.y), hi = pack2bf(f.z, f.w);
  return (unsigned long long)lo | ((unsigned long long)hi << 32);
}

__device__ __forceinline__ f32x4 zero4() {
  f32x4 z; z[0] = 0.f; z[1] = 0.f; z[2] = 0.f; z[3] = 0.f; return z;
}

__device__ __forceinline__ void async_copy16(const void* g, void* l) {
  __builtin_amdgcn_global_load_lds(
      (__attribute__((address_space(1))) void*)(uintptr_t)g,
      (__attribute__((address_space(3))) void*)l, 16, 0, 0);
}

// ---- fused cast: X,W -> bf16; mask -> log2-bias; d_out pre-init with bo ------
__global__ void fused_cast(const float* __restrict__ q, const float* __restrict__ k,
                           const float* __restrict__ v, const float* __restrict__ wq,
                           const float* __restrict__ wk, const float* __restrict__ wv,
                           const float* __restrict__ wo, const int* __restrict__ mask,
                           const float* __restrict__ bo,
                           u16* __restrict__ qo, u16* __restrict__ ko, u16* __restrict__ vo,
                           u16* __restrict__ wqo, u16* __restrict__ wko, u16* __restrict__ wvo,
                           u16* __restrict__ woo, float* __restrict__ biasf,
                           float* __restrict__ dout) {
  const int blk = blockIdx.x;
  if (blk >= 16400) {
    // d_out bias pre-init: 4096 rows x 1024 cols fp32; one row-chunk per block
    const int r = blk - 16400;  // 0..4095
    ((float4*)dout)[r * 256 + threadIdx.x] = ((const float4*)bo)[threadIdx.x];
    return;
  }
  if (blk >= 16384) {
    int i = (blk - 16384) * 256 + threadIdx.x;  // 0..4095
    biasf[i] = mask[i] ? 0.f : -1.4427e20f;
    return;
  }
  const float* src; u16* dst; int off;
  if (blk < 4096)       { src = q;  dst = qo;  off = blk; }
  else if (blk < 8192)  { src = k;  dst = ko;  off = blk - 4096; }
  else if (blk < 12288) { src = v;  dst = vo;  off = blk - 8192; }
  else if (blk < 13312) { src = wq; dst = wqo; off = blk - 12288; }
  else if (blk < 14336) { src = wk; dst = wko; off = blk - 13312; }
  else if (blk < 15360) { src = wv; dst = wvo; off = blk - 14336; }
  else                  { src = wo; dst = woo; off = blk - 15360; }
  const size_t i = (size_t)off * 256 + threadIdx.x;
  ((unsigned long long*)dst)[i] = pack4bf(((const float4*)src)[i]);
}

// ---------------- GEMM core, 32x32x16 MFMA ------------------------------------
// C[i,o] = sum_e A[i,e]*Bw[o,e] (+ bias).  M-tile 128, N-tile NT*64, BK=64.
// A/B frag: m|n = lane&31, k = (lane>>5)*8 + j.
// C/D frag: col = lane&31, row = (reg&3) + 8*(reg>>2) + 4*(lane>>5).
template <bool OUT_BF16, int NT, bool ATOMIC>
__device__ __forceinline__ void gemm_core32(const u16* __restrict__ A,
                                            const u16* __restrict__ Bw,
                                            const float* __restrict__ bias,
                                            void* __restrict__ outp, bool trans,
                                            int m0, int n0, int it0, int itN) {
  __shared__ u16 lA[128 * 64];
  __shared__ u16 lB[NT * 64 * 64];
  const int tid = threadIdx.x;
  const int lane = tid & 63, w = tid >> 6;
  const int wm = w >> 1, wn = w & 1;
  const int l32 = lane & 31, hi = lane >> 5;
  const int rg = lane >> 3, cs = lane & 7;

  f32x16 acc[2][NT];
#pragma unroll
  for (int i = 0; i < 2; ++i)
#pragma unroll
    for (int j = 0; j < NT; ++j)
#pragma unroll
      for (int e = 0; e < 16; ++e) acc[i][j][e] = 0.f;

  for (int it = it0; it < itN; ++it) {
    const int k0 = it * 64;
#pragma unroll
    for (int t = 0; t < 4; ++t) {
      const int row = w * 32 + t * 8 + rg;
      const int c = cs ^ (row & 7);
      async_copy16(A + (size_t)(m0 + row) * 1024 + k0 + c * 8, &lA[(w * 32 + t * 8) * 64]);
    }
#pragma unroll
    for (int t = 0; t < NT * 2; ++t) {
      const int row = w * (NT * 16) + t * 8 + rg;
      const int c = cs ^ (row & 7);
      async_copy16(Bw + (size_t)(n0 + row) * 1024 + k0 + c * 8,
                   &lB[(w * (NT * 16) + t * 8) * 64]);
    }
    __syncthreads();
#pragma unroll
    for (int s = 0; s < 4; ++s) {
      bf16x8 af[2], bfr[NT];
#pragma unroll
      for (int i = 0; i < 2; ++i) {
        const int row = wm * 64 + i * 32 + l32;
        af[i] = *(const bf16x8*)&lA[row * 64 + (((s * 2 + hi) ^ (row & 7)) * 8)];
      }
#pragma unroll
      for (int j = 0; j < NT; ++j) {
        const int row = wn * (NT * 32) + j * 32 + l32;
        bfr[j] = *(const bf16x8*)&lB[row * 64 + (((s * 2 + hi) ^ (row & 7)) * 8)];
      }
#pragma unroll
      for (int i = 0; i < 2; ++i)
#pragma unroll
        for (int j = 0; j < NT; ++j)
          acc[i][j] = __builtin_amdgcn_mfma_f32_32x32x16_bf16(af[i], bfr[j], acc[i][j], 0, 0, 0);
    }
    __syncthreads();
  }

#pragma unroll
  for (int j = 0; j < NT; ++j) {
    const int cg = n0 + wn * (NT * 32) + j * 32 + l32;
    float bj = 0.f;
    if (!ATOMIC) bj = bias[cg];
#pragma unroll
    for (int i = 0; i < 2; ++i) {
      const int mbase = m0 + wm * 64 + i * 32 + 4 * hi;
#pragma unroll
      for (int g = 0; g < 4; ++g) {
        const int r0 = mbase + 8 * g;
        if (ATOMIC) {
          float* o = (float*)outp;
#pragma unroll
          for (int rr = 0; rr < 4; ++rr)
            unsafeAtomicAdd(&o[(size_t)(r0 + rr) * 1024 + cg], acc[i][j][g * 4 + rr]);
        } else if (!trans) {
          if (OUT_BF16) {
            u16* o = (u16*)outp;
#pragma unroll
            for (int rr = 0; rr < 4; ++rr)
              o[(size_t)(r0 + rr) * 1024 + cg] = f2bf(acc[i][j][g * 4 + rr] + bj);
          } else {
            float* o = (float*)outp;
#pragma unroll
            for (int rr = 0; rr < 4; ++rr)
              o[(size_t)(r0 + rr) * 1024 + cg] = acc[i][j][g * 4 + rr] + bj;
          }
        } else {
          // V store in PV-fragment order: Vt2[bh][s>>2][d][s&3]; r0 % 4 == 0.
          u16* o = (u16*)outp;
          const int bh = ((r0 >> 10) << 4) + (cg >> 6);
          const int g2 = (r0 & 1023) >> 2;
          const int d  = cg & 63;
          union { us4_t s; unsigned int u[2]; } pk;
          pk.u[0] = pack2bf(acc[i][j][g * 4 + 0] + bj, acc[i][j][g * 4 + 1] + bj);
          pk.u[1] = pack2bf(acc[i][j][g * 4 + 2] + bj, acc[i][j][g * 4 + 3] + bj);
          *(us4_t*)&o[(size_t)bh * 65536 + g2 * 256 + d * 4] = pk.s;
        }
      }
    }
  }
}

// qkv: grid 768 flat; each XCD owns 12 consecutive (m,z) bands of 8 n-blocks.
__global__ __launch_bounds__(256, 3) void qkv_gemm(
    const u16* __restrict__ Xq, const u16* __restrict__ Xk, const u16* __restrict__ Xv,
    const u16* __restrict__ Wq, const u16* __restrict__ Wk, const u16* __restrict__ Wv,
    const float* __restrict__ bq, const float* __restrict__ bk, const float* __restrict__ bv,
    u16* __restrict__ Qo, u16* __restrict__ Ko, u16* __restrict__ Vto) {
  const int flat = blockIdx.x;
  const int xcd = flat & 7, t = flat >> 3;
  const int n = t & 7, bandl = t >> 3;        // bandl 0..11
  const int band = xcd * 12 + bandl;          // 0..95
  const int z = band >> 5, m = band & 31;
  const u16* A = (z == 0) ? Xq : (z == 1) ? Xk : Xv;
  const u16* W = (z == 0) ? Wq : (z == 1) ? Wk : Wv;
  const float* bias = (z == 0) ? bq : (z == 1) ? bk : bv;
  u16* out = (z == 0) ? Qo : (z == 1) ? Ko : Vto;
  gemm_core32<true, 2, false>(A, W, bias, out, z == 2, m * 128, n * 128, 0, 16);
}

// out: grid 1024 flat; split-K=2, atomic accumulate; 4 blocks/CU.
__global__ __launch_bounds__(256, 4) void out_gemm(
    const u16* __restrict__ A, const u16* __restrict__ W,
    float* __restrict__ out) {
  const int flat = blockIdx.x;
  const int xcd = flat & 7, t = flat >> 3;    // t 0..127
  const int kh = t & 1, s = t >> 1;           // s 0..63
  const int n = s & 15, m = xcd * 4 + (s >> 4);
  gemm_core32<false, 1, true>(A, W, nullptr, out, false, m * 128, n * 64,
                              kh * 8, kh * 8 + 8);
}

// ---------------- flash attention, S^T orientation, no running max ------------
// Grid 1024 (XCD-swizzled). Block 256 = 4 waves x 16 q rows; 128 keys/iter x 8.
__global__ __launch_bounds__(256, 4) void attn_kernel(
    const u16* __restrict__ Qb, const u16* __restrict__ Kb, const u16* __restrict__ Vtb,
    const float* __restrict__ biasf, u16* __restrict__ Ob) {
  __shared__ u16 lK[128 * 64];
  __shared__ u16 lV[64 * 128];  // Vt2 slab, identity layout
  u16* lQ = lV;                 // prologue-only alias

  const int tid = threadIdx.x;
  const int lane = tid & 63, w = tid >> 6;
  const int quad = lane >> 4, l16 = lane & 15;
  const int rg = lane >> 3, cs = lane & 7;

  const int flat = blockIdx.x;
  const int xcd = flat & 7, r = flat >> 3;
  const int bh = xcd * 8 + (r & 7), qt = r >> 3;
  const int b = bh >> 4;
  const size_t qkBase = (size_t)b * 1048576 + (size_t)(bh & 15) * 64;
  const size_t vBase = (size_t)bh * 65536;
  const float C = 0.0450842200277982f;  // (1/sqrt(E)) * log2(e)
  const float* bp = biasf + b * 1024 + quad * 4;

#pragma unroll
  for (int t = 0; t < 2; ++t) {
    const int row = w * 16 + t * 8 + rg;
    const int c = cs ^ (row & 7);
    async_copy16(Qb + qkBase + (size_t)(qt * 64 + row) * 1024 + c * 8,
                 &lQ[(w * 16 + t * 8) * 64]);
  }
  __syncthreads();

  bf16x8 qf[2];
#pragma unroll
  for (int kk = 0; kk < 2; ++kk) {
    const int row = w * 16 + l16;
    qf[kk] = *(const bf16x8*)&lQ[row * 64 + (((kk * 4 + quad) ^ (row & 7)) * 8)];
  }
  __syncthreads();  // protect lQ before lV staging overwrites it

  float lsum = 0.f;
  f32x4 oacc[4];
#pragma unroll
  for (int dt = 0; dt < 4; ++dt) oacc[dt] = zero4();

  for (int it = 0; it < 8; ++it) {
    const int k0 = it * 128;
#pragma unroll
    for (int t = 0; t < 4; ++t) {
      const int row = w * 32 + t * 8 + rg;
      const int c = cs ^ (row & 7);
      async_copy16(Kb + qkBase + (size_t)(k0 + row) * 1024 + c * 8,
                   &lK[(w * 32 + t * 8) * 64]);
    }
#pragma unroll
    for (int t = 0; t < 4; ++t) {
      const int o16 = (w * 4 + t) * 512 + lane * 8;
      async_copy16(Vtb + vBase + (size_t)it * 8192 + o16, &lV[(w * 4 + t) * 512]);
    }
    __syncthreads();

    f32x4 sacc[8];
#pragma unroll
    for (int n = 0; n < 8; ++n) sacc[n] = zero4();
#pragma unroll
    for (int kk = 0; kk < 2; ++kk) {
#pragma unroll
      for (int n = 0; n < 8; ++n) {
        const int row = n * 16 + l16;
        bf16x8 kf = *(const bf16x8*)&lK[row * 64 + (((kk * 4 + quad) ^ (row & 7)) * 8)];
        sacc[n] = __builtin_amdgcn_mfma_f32_16x16x32_bf16(kf, qf[kk], sacc[n], 0, 0, 0);
      }
    }

    f32x4 sum4 = zero4();
#pragma unroll
    for (int n = 0; n < 8; ++n) {
      const float4 vb = *(const float4*)&bp[k0 + n * 16];
      sacc[n][0] = __builtin_amdgcn_exp2f(fmaf(sacc[n][0], C, vb.x));
      sacc[n][1] = __builtin_amdgcn_exp2f(fmaf(sacc[n][1], C, vb.y));
      sacc[n][2] = __builtin_amdgcn_exp2f(fmaf(sacc[n][2], C, vb.z));
      sacc[n][3] = __builtin_amdgcn_exp2f(fmaf(sacc[n][3], C, vb.w));
      sum4[0] += sacc[n][0]; sum4[1] += sacc[n][1];
      sum4[2] += sacc[n][2]; sum4[3] += sacc[n][3];
    }

    s16x4 pf[8];
#pragma unroll
    for (int n = 0; n < 8; ++n) {
      union { s16x4 v; unsigned int u[2]; } pu;
      pu.u[0] = pack2bf(sacc[n][0], sacc[n][1]);
      pu.u[1] = pack2bf(sacc[n][2], sacc[n][3]);
      pf[n] = pu.v;
    }

#pragma unroll
    for (int dt = 0; dt < 4; ++dt) {
      const int dbase = (dt * 16 + l16) * 4;
#pragma unroll
      for (int ks = 0; ks < 8; ++ks) {
        s16x4 vf = *(const s16x4*)&lV[(ks * 4 + quad) * 256 + dbase];
        oacc[dt] = __builtin_amdgcn_mfma_f32_16x16x16bf16_1k(vf, pf[ks], oacc[dt], 0, 0, 0);
      }
    }

    float rs = (sum4[0] + sum4[1]) + (sum4[2] + sum4[3]);
    rs += __shfl_xor(rs, 16);
    rs += __shfl_xor(rs, 32);
    lsum += rs;
    __syncthreads();
  }

  const float inv = 1.f / lsum;
  const int qg = qt * 64 + w * 16 + l16;
#pragma unroll
  for (int dt = 0; dt < 4; ++dt) {
    union { us4_t s; unsigned int u[2]; } pk;
    pk.u[0] = pack2bf(oacc[dt][0] * inv, oacc[dt][1] * inv);
    pk.u[1] = pack2bf(oacc[dt][2] * inv, oacc[dt][3] * inv);
    *(us4_t*)&Ob[qkBase + (size_t)qg * 1024 + dt * 16 + quad * 4] = pk.s;
  }
}

extern "C" void kernel_launch(void* const* d_in, const int* in_sizes, int n_in,
                              void* d_out, int out_size, void* d_ws, size_t ws_size,
                              hipStream_t stream) {
  const float* value  = (const float*)d_in[0];
  const float* key_in = (const float*)d_in[1];
  const float* query  = (const float*)d_in[2];
  const int*   mask   = (const int*)d_in[3];
  const float* Wq = (const float*)d_in[4];
  const float* bq = (const float*)d_in[5];
  const float* Wk = (const float*)d_in[6];
  const float* bk = (const float*)d_in[7];
  const float* Wv = (const float*)d_in[8];
  const float* bv = (const float*)d_in[9];
  const float* Wo = (const float*)d_in[10];
  const float* bo = (const float*)d_in[11];

  u16* ws = (u16*)d_ws;
  u16* q_bf  = ws;              // 4096x1024 (dead after qkv; reused as attnb)
  u16* k_bf  = ws + 4194304;
  u16* v_bf  = ws + 8388608;
  u16* wq_bf = ws + 12582912;   // 1024x1024 each
  u16* wk_bf = ws + 13631488;
  u16* wv_bf = ws + 14680064;
  u16* wo_bf = ws + 15728640;
  u16* Qbuf  = ws + 16777216;   // (b,s,h*64+d)
  u16* Kbuf  = ws + 20971520;
  u16* Vtbuf = ws + 25165824;   // Vt2[bh][s>>2][d][s&3]
  u16* attnb = q_bf;            // alias: q_bf consumed by qkv_gemm
  float* biasf = (float*)(ws + 29360128);  // 4096 floats
  float* dout = (float*)d_out;

  fused_cast<<<20496, 256, 0, stream>>>(query, key_in, value, Wq, Wk, Wv, Wo, mask,
                                        bo, q_bf, k_bf, v_bf, wq_bf, wk_bf, wv_bf,
                                        wo_bf, biasf, dout);
  qkv_gemm<<<dim3(768), 256, 0, stream>>>(q_bf, k_bf, v_bf, wq_bf, wk_bf, wv_bf,
                                          bq, bk, bv, Qbuf, Kbuf, Vtbuf);
  attn_kernel<<<dim3(1024), 256, 0, stream>>>(Qbuf, Kbuf, Vtbuf, biasf, attnb);
  out_gemm<<<dim3(1024), 256, 0, stream>>>(attnb, wo_bf, dout);
}